// Round 2
// baseline (475.087 us; speedup 1.0000x reference)
//
#include <hip/hip_runtime.h>
#include <hip/hip_bf16.h>

typedef __attribute__((ext_vector_type(8))) short bf16x8;
typedef __attribute__((ext_vector_type(4))) float f32x4;
typedef unsigned short u16;

#define DEV static __device__ __forceinline__

DEV u16 f2bf(float f) {
  union { float f; unsigned u; } v; v.f = f;
  return (u16)((v.u + 0x7FFFu + ((v.u >> 16) & 1u)) >> 16);
}

// ---------------------------------------------------------------- convert
// x: 4*2048*512 f32 -> bf16 ; Wq/Wk/Wv -> Wb[1536][512] ; Wo -> Wob[512][512]
__global__ __launch_bounds__(256) void cvt_kernel(
    const float* __restrict__ x, const float* __restrict__ Wq,
    const float* __restrict__ Wk, const float* __restrict__ Wv,
    const float* __restrict__ Wo, u16* __restrict__ xb,
    u16* __restrict__ Wb, u16* __restrict__ Wob) {
  int g = blockIdx.x * 256 + threadIdx.x;
  if (g < 1048576) {  // x: 4194304 / 4
    float4 v = ((const float4*)x)[g];
    ushort4 o;
    o.x = f2bf(v.x); o.y = f2bf(v.y); o.z = f2bf(v.z); o.w = f2bf(v.w);
    ((ushort4*)xb)[g] = o;
  } else {
    int t = g - 1048576;           // 4 * 65536 weight groups
    int w = t >> 16;
    int off = t & 65535;
    const float* src = (w == 0) ? Wq : (w == 1) ? Wk : (w == 2) ? Wv : Wo;
    u16* dst = (w < 3) ? (Wb + (size_t)w * 262144) : Wob;
    float4 v = ((const float4*)src)[off];
    ushort4 o;
    o.x = f2bf(v.x); o.y = f2bf(v.y); o.z = f2bf(v.z); o.w = f2bf(v.w);
    ((ushort4*)dst)[off] = o;
  }
}

// ---------------------------------------------------------------- QKV GEMM
// C[8192][1536] = xb[8192][512] @ Wb[1536][512]^T + bias
// n<1024 -> QK[m][n] (Q cols 0-511, K cols 512-1023), n>=1024 -> Vt transposed
__global__ __launch_bounds__(256) void gemm_qkv(
    const u16* __restrict__ xb, const u16* __restrict__ Wb,
    const float* __restrict__ bq, const float* __restrict__ bk,
    const float* __restrict__ bv, u16* __restrict__ QK, u16* __restrict__ Vt) {
  __shared__ __align__(16) u16 As[128 * 32];
  __shared__ __align__(16) u16 Bs[128 * 32];
  const int tid = threadIdx.x, lane = tid & 63, wv = tid >> 6;
  const int fr = lane & 15, fg = lane >> 4;
  const int wr = wv >> 1, wc = wv & 1;
  const int m0 = blockIdx.x * 128, n0 = blockIdx.y * 128;
  f32x4 acc[4][4] = {};
  const int c0 = wv * 128;
  for (int kt = 0; kt < 512; kt += 32) {
#pragma unroll
    for (int i = 0; i < 2; ++i) {
      int c = c0 + i * 64 + lane;
      int row = c >> 2, cg = c & 3;
      const u16* ga = xb + (size_t)(m0 + row) * 512 + kt + cg * 8;
      const u16* gb = Wb + (size_t)(n0 + row) * 512 + kt + cg * 8;
      __builtin_amdgcn_global_load_lds(
          (const __attribute__((address_space(1))) void*)ga,
          (__attribute__((address_space(3))) void*)(As + (c0 + i * 64) * 8), 16, 0, 0);
      __builtin_amdgcn_global_load_lds(
          (const __attribute__((address_space(1))) void*)gb,
          (__attribute__((address_space(3))) void*)(Bs + (c0 + i * 64) * 8), 16, 0, 0);
    }
    __syncthreads();
    bf16x8 af[4], bf[4];
#pragma unroll
    for (int mi = 0; mi < 4; ++mi)
      af[mi] = *(const bf16x8*)(As + (wr * 64 + mi * 16 + fr) * 32 + fg * 8);
#pragma unroll
    for (int ni = 0; ni < 4; ++ni)
      bf[ni] = *(const bf16x8*)(Bs + (wc * 64 + ni * 16 + fr) * 32 + fg * 8);
#pragma unroll
    for (int mi = 0; mi < 4; ++mi)
#pragma unroll
      for (int ni = 0; ni < 4; ++ni)
        acc[mi][ni] = __builtin_amdgcn_mfma_f32_16x16x32_bf16(af[mi], bf[ni], acc[mi][ni], 0, 0, 0);
    __syncthreads();
  }
#pragma unroll
  for (int ni = 0; ni < 4; ++ni) {
    int n = n0 + wc * 64 + ni * 16 + fr;
    float bias = (n < 512) ? bq[n] : (n < 1024) ? bk[n - 512] : bv[n - 1024];
#pragma unroll
    for (int mi = 0; mi < 4; ++mi) {
#pragma unroll
      for (int r = 0; r < 4; ++r) {
        int m = m0 + wr * 64 + mi * 16 + fg * 4 + r;
        u16 val = f2bf(acc[mi][ni][r] + bias);
        if (n < 1024)
          QK[(size_t)m * 1024 + n] = val;
        else {
          int bb = m >> 11, t = m & 2047;
          Vt[((size_t)bb * 512 + (n - 1024)) * 2048 + t] = val;
        }
      }
    }
  }
}

// ---------------------------------------------------------------- attention
// 1024 blocks (XCD-swizzled), 4 waves/block, 16 q-rows per wave, no barriers.
// Direct-exp softmax: S bounded above (~+3), below (~-21 at row max), so no
// online max tracking needed -- s = sum exp(S) is overflow/underflow-safe.
__global__ __launch_bounds__(256) void attn_kernel(
    const u16* __restrict__ QK, const u16* __restrict__ Vt,
    const unsigned char* __restrict__ mask, float* __restrict__ attn,
    u16* __restrict__ ctx) {
  __shared__ __align__(16) u16 PL[4][16][32];
  const int tid = threadIdx.x, lane = tid & 63, wv = tid >> 6;
  const int fr = lane & 15, fg = lane >> 4;
  const int bid = blockIdx.x;
  const int swz = (bid & 7) * 128 + (bid >> 3);  // XCD-contiguous heads
  const int b = swz >> 8, h = (swz >> 5) & 7, qt = swz & 31;
  const int q0 = qt * 64 + wv * 16;
  const size_t tok0 = (size_t)b * 2048;
  const u16* Qbase = QK + tok0 * 1024 + h * 64;
  const u16* Kbase = QK + tok0 * 1024 + 512 + h * 64;
  const u16* Vbase = Vt + ((size_t)b * 512 + h * 64) * 2048;

  bf16x8 aq[2];
#pragma unroll
  for (int c = 0; c < 2; ++c)
    aq[c] = *(const bf16x8*)(Qbase + (size_t)(q0 + fr) * 1024 + c * 32 + fg * 8);
  const float iif = (float)(q0 + fg * 4);

  float srow[4] = {0.f, 0.f, 0.f, 0.f};

  // ---- pass A: row exp-sums (prefetched K fragments)
  const u16* kptr = Kbase + (size_t)fr * 1024;
  bf16x8 kf0 = *(const bf16x8*)(kptr + fg * 8);
  bf16x8 kf1 = *(const bf16x8*)(kptr + 32 + fg * 8);
  for (int kt = 0; kt < 128; ++kt) {
    const u16* knp = kptr + 16 * 1024;            // next tile (over-read safe: Vt follows QK)
    bf16x8 kn0 = *(const bf16x8*)(knp + fg * 8);
    bf16x8 kn1 = *(const bf16x8*)(knp + 32 + fg * 8);
    const int key = kt * 16 + fr;
    float cutb = -0.5f * fabsf((float)key - 1024.0f);
    if (mask[tok0 + key]) cutb = -1e30f;
    f32x4 a = {0.f, 0.f, 0.f, 0.f};
    a = __builtin_amdgcn_mfma_f32_16x16x32_bf16(aq[0], kf0, a, 0, 0, 0);
    a = __builtin_amdgcn_mfma_f32_16x16x32_bf16(aq[1], kf1, a, 0, 0, 0);
    const float keyf = (float)key;
#pragma unroll
    for (int r = 0; r < 4; ++r) {
      float S = fmaf(a[r], 0.125f, fmaf(-0.02f, fabsf(iif + (float)r - keyf), cutb));
      srow[r] += __expf(S);
    }
    kf0 = kn0; kf1 = kn1; kptr = knp;
  }
  // sum across the 16 lanes of each fg group (keys)
#pragma unroll
  for (int d = 1; d < 16; d <<= 1)
#pragma unroll
    for (int i = 0; i < 4; ++i)
      srow[i] += __shfl_xor(srow[i], d, 64);
  float rinv[4];
#pragma unroll
  for (int i = 0; i < 4; ++i) rinv[i] = 1.0f / srow[i];

  f32x4 cacc[4] = {};
  float* attn_bh = attn + ((size_t)b * 8 + h) * 2048 * 2048;

  // ---- pass B: recompute S, write normalized P, accumulate PV
  for (int kc = 0; kc < 64; ++kc) {
    const int kk0 = kc * 32;
    // all global loads for this tile issued up front
    const u16* kp0 = Kbase + (size_t)(kk0 + fr) * 1024;
    const u16* kp1 = kp0 + 16 * 1024;
    bf16x8 ka0 = *(const bf16x8*)(kp0 + fg * 8);
    bf16x8 ka1 = *(const bf16x8*)(kp0 + 32 + fg * 8);
    bf16x8 kb0 = *(const bf16x8*)(kp1 + fg * 8);
    bf16x8 kb1 = *(const bf16x8*)(kp1 + 32 + fg * 8);
    bf16x8 vf[4];
#pragma unroll
    for (int c4 = 0; c4 < 4; ++c4)
      vf[c4] = *(const bf16x8*)(Vbase + (size_t)(c4 * 16 + fr) * 2048 + kk0 + fg * 8);

    f32x4 a0 = {0.f, 0.f, 0.f, 0.f}, a1 = {0.f, 0.f, 0.f, 0.f};
    a0 = __builtin_amdgcn_mfma_f32_16x16x32_bf16(aq[0], ka0, a0, 0, 0, 0);
    a0 = __builtin_amdgcn_mfma_f32_16x16x32_bf16(aq[1], ka1, a0, 0, 0, 0);
    a1 = __builtin_amdgcn_mfma_f32_16x16x32_bf16(aq[0], kb0, a1, 0, 0, 0);
    a1 = __builtin_amdgcn_mfma_f32_16x16x32_bf16(aq[1], kb1, a1, 0, 0, 0);

#pragma unroll
    for (int t = 0; t < 2; ++t) {
      const int key = kk0 + t * 16 + fr;
      float cutb = -0.5f * fabsf((float)key - 1024.0f);
      if (mask[tok0 + key]) cutb = -1e30f;
      const float keyf = (float)key;
      const f32x4& a = t ? a1 : a0;
#pragma unroll
      for (int r = 0; r < 4; ++r) {
        float S = fmaf(a[r], 0.125f, fmaf(-0.02f, fabsf(iif + (float)r - keyf), cutb));
        float P = __expf(S) * rinv[r];
        attn_bh[(size_t)(q0 + fg * 4 + r) * 2048 + key] = P;
        PL[wv][fg * 4 + r][t * 16 + fr] = f2bf(P);
      }
    }
    bf16x8 pa = *(const bf16x8*)(&PL[wv][fr][fg * 8]);
#pragma unroll
    for (int c4 = 0; c4 < 4; ++c4)
      cacc[c4] = __builtin_amdgcn_mfma_f32_16x16x32_bf16(pa, vf[c4], cacc[c4], 0, 0, 0);
  }
  // ctx out (bf16, [8192][512])
#pragma unroll
  for (int c4 = 0; c4 < 4; ++c4)
#pragma unroll
    for (int r = 0; r < 4; ++r) {
      int q = q0 + fg * 4 + r;
      ctx[(tok0 + q) * 512 + h * 64 + c4 * 16 + fr] = f2bf(cacc[c4][r]);
    }
}

// ---------------------------------------------------------------- out GEMM
// out[8192][512] = ctx[8192][512] @ Wob[512][512]^T + bo  (fp32 out)
// 64x64 tiles -> 1024 blocks (4/CU) for latency hiding.
__global__ __launch_bounds__(256) void gemm_out(
    const u16* __restrict__ ctx, const u16* __restrict__ Wob,
    const float* __restrict__ bo, float* __restrict__ out) {
  __shared__ __align__(16) u16 As[64 * 32];
  __shared__ __align__(16) u16 Bs[64 * 32];
  const int tid = threadIdx.x, lane = tid & 63, wv = tid >> 6;
  const int fr = lane & 15, fg = lane >> 4;
  const int wr = wv >> 1, wc = wv & 1;
  const int m0 = blockIdx.x * 64, n0 = blockIdx.y * 64;
  f32x4 acc[2][2] = {};
  for (int kt = 0; kt < 512; kt += 32) {
    {
      int row = tid >> 2, cg = tid & 3;
      const u16* ga = ctx + (size_t)(m0 + row) * 512 + kt + cg * 8;
      const u16* gb = Wob + (size_t)(n0 + row) * 512 + kt + cg * 8;
      __builtin_amdgcn_global_load_lds(
          (const __attribute__((address_space(1))) void*)ga,
          (__attribute__((address_space(3))) void*)(As + tid * 8), 16, 0, 0);
      __builtin_amdgcn_global_load_lds(
          (const __attribute__((address_space(1))) void*)gb,
          (__attribute__((address_space(3))) void*)(Bs + tid * 8), 16, 0, 0);
    }
    __syncthreads();
    bf16x8 af[2], bf[2];
#pragma unroll
    for (int mi = 0; mi < 2; ++mi)
      af[mi] = *(const bf16x8*)(As + (wr * 32 + mi * 16 + fr) * 32 + fg * 8);
#pragma unroll
    for (int ni = 0; ni < 2; ++ni)
      bf[ni] = *(const bf16x8*)(Bs + (wc * 32 + ni * 16 + fr) * 32 + fg * 8);
#pragma unroll
    for (int mi = 0; mi < 2; ++mi)
#pragma unroll
      for (int ni = 0; ni < 2; ++ni)
        acc[mi][ni] = __builtin_amdgcn_mfma_f32_16x16x32_bf16(af[mi], bf[ni], acc[mi][ni], 0, 0, 0);
    __syncthreads();
  }
#pragma unroll
  for (int ni = 0; ni < 2; ++ni) {
    int n = n0 + wc * 32 + ni * 16 + fr;
    float bias = bo[n];
#pragma unroll
    for (int mi = 0; mi < 2; ++mi)
#pragma unroll
      for (int r = 0; r < 4; ++r) {
        int m = m0 + wr * 32 + mi * 16 + fg * 4 + r;
        out[(size_t)m * 512 + n] = acc[mi][ni][r] + bias;
      }
  }
}

// ---------------------------------------------------------------- launcher
extern "C" void kernel_launch(void* const* d_in, const int* in_sizes, int n_in,
                              void* d_out, int out_size, void* d_ws, size_t ws_size,
                              hipStream_t stream) {
  const float* x = (const float*)d_in[0];
  const unsigned char* mask = (const unsigned char*)d_in[1];
  const float* Wq = (const float*)d_in[2];
  const float* bq = (const float*)d_in[3];
  const float* Wk = (const float*)d_in[4];
  const float* bk = (const float*)d_in[5];
  const float* Wv = (const float*)d_in[6];
  const float* bv = (const float*)d_in[7];
  const float* Wo = (const float*)d_in[8];
  const float* bo = (const float*)d_in[9];
  float* out = (float*)d_out;
  float* attn = out + (size_t)4 * 2048 * 512;

  char* ws = (char*)d_ws;
  size_t off = 0;
  u16* xb  = (u16*)(ws + off); off += (size_t)8192 * 512 * 2;   // x bf16
  u16* Wb  = (u16*)(ws + off); off += (size_t)1536 * 512 * 2;   // Wq|Wk|Wv bf16
  u16* Wob = (u16*)(ws + off); off += (size_t)512 * 512 * 2;    // Wo bf16
  u16* QK  = (u16*)(ws + off); off += (size_t)8192 * 1024 * 2;  // Q|K bf16
  u16* Vt  = (u16*)(ws + off); off += (size_t)2048 * 2048 * 2;  // V transposed (after QK: pass-A over-read safe)
  u16* ctx = (u16*)(ws + off); off += (size_t)8192 * 512 * 2;   // attn@V bf16
  if (ws_size < off) return;  // insufficient workspace

  cvt_kernel<<<5120, 256, 0, stream>>>(x, Wq, Wk, Wv, Wo, xb, Wb, Wob);
  gemm_qkv<<<dim3(64, 12), 256, 0, stream>>>(xb, Wb, bq, bk, bv, QK, Vt);
  attn_kernel<<<1024, 256, 0, stream>>>(QK, Vt, mask, attn, ctx);
  gemm_out<<<dim3(128, 8), 256, 0, stream>>>(ctx, Wob, bo, out);
}

// Round 3
// 259.295 us; speedup vs baseline: 1.8322x; 1.8322x over previous
//
#include <hip/hip_runtime.h>
#include <hip/hip_bf16.h>

typedef __attribute__((ext_vector_type(8))) short bf16x8;
typedef __attribute__((ext_vector_type(4))) float f32x4;
typedef unsigned short u16;

#define DEV static __device__ __forceinline__

DEV u16 f2bf(float f) {
  union { float f; unsigned u; } v; v.f = f;
  return (u16)((v.u + 0x7FFFu + ((v.u >> 16) & 1u)) >> 16);
}

// ---------------------------------------------------------------- convert
__global__ __launch_bounds__(256) void cvt_kernel(
    const float* __restrict__ x, const float* __restrict__ Wq,
    const float* __restrict__ Wk, const float* __restrict__ Wv,
    const float* __restrict__ Wo, u16* __restrict__ xb,
    u16* __restrict__ Wb, u16* __restrict__ Wob) {
  int g = blockIdx.x * 256 + threadIdx.x;
  if (g < 1048576) {
    float4 v = ((const float4*)x)[g];
    ushort4 o;
    o.x = f2bf(v.x); o.y = f2bf(v.y); o.z = f2bf(v.z); o.w = f2bf(v.w);
    ((ushort4*)xb)[g] = o;
  } else {
    int t = g - 1048576;
    int w = t >> 16;
    int off = t & 65535;
    const float* src = (w == 0) ? Wq : (w == 1) ? Wk : (w == 2) ? Wv : Wo;
    u16* dst = (w < 3) ? (Wb + (size_t)w * 262144) : Wob;
    float4 v = ((const float4*)src)[off];
    ushort4 o;
    o.x = f2bf(v.x); o.y = f2bf(v.y); o.z = f2bf(v.z); o.w = f2bf(v.w);
    ((ushort4*)dst)[off] = o;
  }
}

// ---------------------------------------------------------------- QKV GEMM
__global__ __launch_bounds__(256) void gemm_qkv(
    const u16* __restrict__ xb, const u16* __restrict__ Wb,
    const float* __restrict__ bq, const float* __restrict__ bk,
    const float* __restrict__ bv, u16* __restrict__ QK, u16* __restrict__ Vt) {
  __shared__ __align__(16) u16 As[128 * 32];
  __shared__ __align__(16) u16 Bs[128 * 32];
  const int tid = threadIdx.x, lane = tid & 63, wv = tid >> 6;
  const int fr = lane & 15, fg = lane >> 4;
  const int wr = wv >> 1, wc = wv & 1;
  const int m0 = blockIdx.x * 128, n0 = blockIdx.y * 128;
  f32x4 acc[4][4] = {};
  const int c0 = wv * 128;
  for (int kt = 0; kt < 512; kt += 32) {
#pragma unroll
    for (int i = 0; i < 2; ++i) {
      int c = c0 + i * 64 + lane;
      int row = c >> 2, cg = c & 3;
      const u16* ga = xb + (size_t)(m0 + row) * 512 + kt + cg * 8;
      const u16* gb = Wb + (size_t)(n0 + row) * 512 + kt + cg * 8;
      __builtin_amdgcn_global_load_lds(
          (const __attribute__((address_space(1))) void*)ga,
          (__attribute__((address_space(3))) void*)(As + (c0 + i * 64) * 8), 16, 0, 0);
      __builtin_amdgcn_global_load_lds(
          (const __attribute__((address_space(1))) void*)gb,
          (__attribute__((address_space(3))) void*)(Bs + (c0 + i * 64) * 8), 16, 0, 0);
    }
    __syncthreads();
    bf16x8 af[4], bf[4];
#pragma unroll
    for (int mi = 0; mi < 4; ++mi)
      af[mi] = *(const bf16x8*)(As + (wr * 64 + mi * 16 + fr) * 32 + fg * 8);
#pragma unroll
    for (int ni = 0; ni < 4; ++ni)
      bf[ni] = *(const bf16x8*)(Bs + (wc * 64 + ni * 16 + fr) * 32 + fg * 8);
#pragma unroll
    for (int mi = 0; mi < 4; ++mi)
#pragma unroll
      for (int ni = 0; ni < 4; ++ni)
        acc[mi][ni] = __builtin_amdgcn_mfma_f32_16x16x32_bf16(af[mi], bf[ni], acc[mi][ni], 0, 0, 0);
    __syncthreads();
  }
#pragma unroll
  for (int ni = 0; ni < 4; ++ni) {
    int n = n0 + wc * 64 + ni * 16 + fr;
    float bias = (n < 512) ? bq[n] : (n < 1024) ? bk[n - 512] : bv[n - 1024];
#pragma unroll
    for (int mi = 0; mi < 4; ++mi) {
#pragma unroll
      for (int r = 0; r < 4; ++r) {
        int m = m0 + wr * 64 + mi * 16 + fg * 4 + r;
        u16 val = f2bf(acc[mi][ni][r] + bias);
        if (n < 1024)
          QK[(size_t)m * 1024 + n] = val;
        else {
          int bb = m >> 11, t = m & 2047;
          Vt[((size_t)bb * 512 + (n - 1024)) * 2048 + t] = val;
        }
      }
    }
  }
}

// ---------------------------------------------------------------- attention
// 512 blocks x 512 threads. Block = (b,h, 128 q-rows); 8 waves x 16 q-rows.
// K/V tiles (64 keys) staged in LDS via coalesced global_load_lds, double
// buffered, XOR-swizzled (c ^= row&7 on 16B units, applied to the GLOBAL
// source; LDS dest stays linear). Two passes: A = row exp-sums, B = write
// normalized P (nontemporal) + PV accumulate.
__global__ __launch_bounds__(512) void attn_kernel(
    const u16* __restrict__ QK, const u16* __restrict__ Vt,
    const unsigned char* __restrict__ mask, float* __restrict__ attn,
    u16* __restrict__ ctx) {
  __shared__ __align__(16) u16 Kb[2][4096];   // [64 keys][64 dh] swizzled
  __shared__ __align__(16) u16 Vb[2][4096];   // [64 dh][64 keys] swizzled
  __shared__ __align__(16) u16 PL[8][1152];   // per-wave P tile, stride 72
  const int tid = threadIdx.x, lane = tid & 63, wv = tid >> 6;
  const int fr = lane & 15, fg = lane >> 4;
  const int bid = blockIdx.x;
  const int swz = (bid & 7) * 64 + (bid >> 3);   // XCD-contiguous (b,h)
  const int b = swz >> 7, h = (swz >> 4) & 7, qt = swz & 15;
  const int q0 = qt * 128 + wv * 16;
  const size_t tok0 = (size_t)b * 2048;
  const u16* Qbase = QK + tok0 * 1024 + h * 64;
  const u16* Kbase = QK + tok0 * 1024 + 512 + h * 64;
  const u16* Vbase = Vt + ((size_t)b * 512 + h * 64) * 2048;

  // staging decomposition: 512 threads x 16B cover one 64x64 bf16 tile
  const int srow = tid >> 3, ss = tid & 7, sc = ss ^ (srow & 7);
  const int ldsu = (wv * 64) * 8;  // wave-uniform LDS base (u16 units)

#define STAGE_K(kb0, buf)                                                     \
  __builtin_amdgcn_global_load_lds(                                           \
      (const __attribute__((address_space(1))) void*)(                        \
          Kbase + (size_t)((kb0) + srow) * 1024 + sc * 8),                    \
      (__attribute__((address_space(3))) void*)(Kb[buf] + ldsu), 16, 0, 0)
#define STAGE_V(kb0, buf)                                                     \
  __builtin_amdgcn_global_load_lds(                                           \
      (const __attribute__((address_space(1))) void*)(                        \
          Vbase + (size_t)srow * 2048 + (kb0) + sc * 8),                      \
      (__attribute__((address_space(3))) void*)(Vb[buf] + ldsu), 16, 0, 0)

  bf16x8 aq[2];
#pragma unroll
  for (int c = 0; c < 2; ++c)
    aq[c] = *(const bf16x8*)(Qbase + (size_t)(q0 + fr) * 1024 + c * 32 + fg * 8);
  const float iif = (float)(q0 + fg * 4);

  float srw[4] = {0.f, 0.f, 0.f, 0.f};

  // ---- pass A: row exp-sums
  STAGE_K(0, 0);
  __syncthreads();
  for (int t = 0; t < 32; ++t) {
    const int cur = t & 1;
    if (t < 31) STAGE_K((t + 1) * 64, cur ^ 1);
    const int keybase = t * 64;
    const u16* KL = Kb[cur];
#pragma unroll
    for (int kb = 0; kb < 4; ++kb) {
      const int row = kb * 16 + fr;
      const int rx = row & 7;
      bf16x8 k0 = *(const bf16x8*)(KL + row * 64 + ((fg ^ rx) * 8));
      bf16x8 k1 = *(const bf16x8*)(KL + row * 64 + (((4 + fg) ^ rx) * 8));
      f32x4 a = {0.f, 0.f, 0.f, 0.f};
      a = __builtin_amdgcn_mfma_f32_16x16x32_bf16(aq[0], k0, a, 0, 0, 0);
      a = __builtin_amdgcn_mfma_f32_16x16x32_bf16(aq[1], k1, a, 0, 0, 0);
      const int key = keybase + kb * 16 + fr;
      float cutb = -0.5f * fabsf((float)key - 1024.0f);
      if (mask[tok0 + key]) cutb = -1e30f;
      const float dif = iif - (float)key;
#pragma unroll
      for (int r = 0; r < 4; ++r) {
        float S = fmaf(a[r], 0.125f, fmaf(-0.02f, fabsf(dif + (float)r), cutb));
        srw[r] += __expf(S);
      }
    }
    __syncthreads();
  }
  // reduce over the 16 fr lanes
#pragma unroll
  for (int d = 1; d < 16; d <<= 1)
#pragma unroll
    for (int i = 0; i < 4; ++i)
      srw[i] += __shfl_xor(srw[i], d, 64);
  float rinv[4];
#pragma unroll
  for (int i = 0; i < 4; ++i) rinv[i] = 1.0f / srw[i];

  // ---- pass B: normalized P writes + PV
  f32x4 cacc[4] = {};
  float* attn_bh = attn + ((size_t)b * 8 + h) * 2048 * 2048;
  float* arow[4];
#pragma unroll
  for (int r = 0; r < 4; ++r) arow[r] = attn_bh + (size_t)(q0 + fg * 4 + r) * 2048;

  STAGE_K(0, 0);
  STAGE_V(0, 0);
  __syncthreads();
  for (int t = 0; t < 32; ++t) {
    const int cur = t & 1;
    if (t < 31) { STAGE_K((t + 1) * 64, cur ^ 1); STAGE_V((t + 1) * 64, cur ^ 1); }
    const int keybase = t * 64;
    const u16* KL = Kb[cur];
    const u16* VL = Vb[cur];
#pragma unroll
    for (int kb = 0; kb < 4; ++kb) {
      const int row = kb * 16 + fr;
      const int rx = row & 7;
      bf16x8 k0 = *(const bf16x8*)(KL + row * 64 + ((fg ^ rx) * 8));
      bf16x8 k1 = *(const bf16x8*)(KL + row * 64 + (((4 + fg) ^ rx) * 8));
      f32x4 a = {0.f, 0.f, 0.f, 0.f};
      a = __builtin_amdgcn_mfma_f32_16x16x32_bf16(aq[0], k0, a, 0, 0, 0);
      a = __builtin_amdgcn_mfma_f32_16x16x32_bf16(aq[1], k1, a, 0, 0, 0);
      const int key = keybase + kb * 16 + fr;
      float cutb = -0.5f * fabsf((float)key - 1024.0f);
      if (mask[tok0 + key]) cutb = -1e30f;
      const float dif = iif - (float)key;
#pragma unroll
      for (int r = 0; r < 4; ++r) {
        float S = fmaf(a[r], 0.125f, fmaf(-0.02f, fabsf(dif + (float)r), cutb));
        float P = __expf(S) * rinv[r];
        __builtin_nontemporal_store(P, arow[r] + key);
        PL[wv][(fg * 4 + r) * 72 + kb * 16 + fr] = f2bf(P);
      }
    }
#pragma unroll
    for (int kc = 0; kc < 2; ++kc) {
      bf16x8 pa = *(const bf16x8*)(PL[wv] + fr * 72 + kc * 32 + fg * 8);
#pragma unroll
      for (int c4 = 0; c4 < 4; ++c4) {
        const int vrow = c4 * 16 + fr;
        bf16x8 vf = *(const bf16x8*)(VL + vrow * 64 + ((((kc * 4 + fg)) ^ (vrow & 7)) * 8));
        cacc[c4] = __builtin_amdgcn_mfma_f32_16x16x32_bf16(pa, vf, cacc[c4], 0, 0, 0);
      }
    }
    __syncthreads();
  }
  // ctx out (bf16, [8192][512]); P already normalized
#pragma unroll
  for (int c4 = 0; c4 < 4; ++c4)
#pragma unroll
    for (int r = 0; r < 4; ++r) {
      int q = q0 + fg * 4 + r;
      ctx[(tok0 + q) * 512 + h * 64 + c4 * 16 + fr] = f2bf(cacc[c4][r]);
    }
#undef STAGE_K
#undef STAGE_V
}

// ---------------------------------------------------------------- out GEMM
__global__ __launch_bounds__(256) void gemm_out(
    const u16* __restrict__ ctx, const u16* __restrict__ Wob,
    const float* __restrict__ bo, float* __restrict__ out) {
  __shared__ __align__(16) u16 As[64 * 32];
  __shared__ __align__(16) u16 Bs[64 * 32];
  const int tid = threadIdx.x, lane = tid & 63, wv = tid >> 6;
  const int fr = lane & 15, fg = lane >> 4;
  const int wr = wv >> 1, wc = wv & 1;
  const int m0 = blockIdx.x * 64, n0 = blockIdx.y * 64;
  f32x4 acc[2][2] = {};
  for (int kt = 0; kt < 512; kt += 32) {
    {
      int row = tid >> 2, cg = tid & 3;
      const u16* ga = ctx + (size_t)(m0 + row) * 512 + kt + cg * 8;
      const u16* gb = Wob + (size_t)(n0 + row) * 512 + kt + cg * 8;
      __builtin_amdgcn_global_load_lds(
          (const __attribute__((address_space(1))) void*)ga,
          (__attribute__((address_space(3))) void*)(As + tid * 8), 16, 0, 0);
      __builtin_amdgcn_global_load_lds(
          (const __attribute__((address_space(1))) void*)gb,
          (__attribute__((address_space(3))) void*)(Bs + tid * 8), 16, 0, 0);
    }
    __syncthreads();
    bf16x8 af[2], bf[2];
#pragma unroll
    for (int mi = 0; mi < 2; ++mi)
      af[mi] = *(const bf16x8*)(As + (wr * 32 + mi * 16 + fr) * 32 + fg * 8);
#pragma unroll
    for (int ni = 0; ni < 2; ++ni)
      bf[ni] = *(const bf16x8*)(Bs + (wc * 32 + ni * 16 + fr) * 32 + fg * 8);
#pragma unroll
    for (int mi = 0; mi < 2; ++mi)
#pragma unroll
      for (int ni = 0; ni < 2; ++ni)
        acc[mi][ni] = __builtin_amdgcn_mfma_f32_16x16x32_bf16(af[mi], bf[ni], acc[mi][ni], 0, 0, 0);
    __syncthreads();
  }
#pragma unroll
  for (int ni = 0; ni < 2; ++ni) {
    int n = n0 + wc * 32 + ni * 16 + fr;
    float bias = bo[n];
#pragma unroll
    for (int mi = 0; mi < 2; ++mi)
#pragma unroll
      for (int r = 0; r < 4; ++r) {
        int m = m0 + wr * 32 + mi * 16 + fg * 4 + r;
        out[(size_t)m * 512 + n] = acc[mi][ni][r] + bias;
      }
  }
}

// ---------------------------------------------------------------- launcher
extern "C" void kernel_launch(void* const* d_in, const int* in_sizes, int n_in,
                              void* d_out, int out_size, void* d_ws, size_t ws_size,
                              hipStream_t stream) {
  const float* x = (const float*)d_in[0];
  const unsigned char* mask = (const unsigned char*)d_in[1];
  const float* Wq = (const float*)d_in[2];
  const float* bq = (const float*)d_in[3];
  const float* Wk = (const float*)d_in[4];
  const float* bk = (const float*)d_in[5];
  const float* Wv = (const float*)d_in[6];
  const float* bv = (const float*)d_in[7];
  const float* Wo = (const float*)d_in[8];
  const float* bo = (const float*)d_in[9];
  float* out = (float*)d_out;
  float* attn = out + (size_t)4 * 2048 * 512;

  char* ws = (char*)d_ws;
  size_t off = 0;
  u16* xb  = (u16*)(ws + off); off += (size_t)8192 * 512 * 2;
  u16* Wb  = (u16*)(ws + off); off += (size_t)1536 * 512 * 2;
  u16* Wob = (u16*)(ws + off); off += (size_t)512 * 512 * 2;
  u16* QK  = (u16*)(ws + off); off += (size_t)8192 * 1024 * 2;
  u16* Vt  = (u16*)(ws + off); off += (size_t)2048 * 2048 * 2;
  u16* ctx = (u16*)(ws + off); off += (size_t)8192 * 512 * 2;
  if (ws_size < off) return;

  cvt_kernel<<<5120, 256, 0, stream>>>(x, Wq, Wk, Wv, Wo, xb, Wb, Wob);
  gemm_qkv<<<dim3(64, 12), 256, 0, stream>>>(xb, Wb, bq, bk, bv, QK, Vt);
  attn_kernel<<<512, 512, 0, stream>>>(QK, Vt, mask, attn, ctx);
  gemm_out<<<dim3(128, 8), 256, 0, stream>>>(ctx, Wob, bo, out);
}

// Round 4
// 250.075 us; speedup vs baseline: 1.8998x; 1.0369x over previous
//
#include <hip/hip_runtime.h>
#include <hip/hip_bf16.h>

typedef __attribute__((ext_vector_type(8))) short bf16x8;
typedef __attribute__((ext_vector_type(4))) float f32x4;
typedef unsigned short u16;

#define DEV static __device__ __forceinline__

DEV u16 f2bf(float f) {
  union { float f; unsigned u; } v; v.f = f;
  return (u16)((v.u + 0x7FFFu + ((v.u >> 16) & 1u)) >> 16);
}

// ---------------------------------------------------------------- convert
// x -> bf16 ; Wq/Wk/Wv -> Wb[1536][512] ; Wo -> Wob ; cutb[b][key] bias table
__global__ __launch_bounds__(256) void cvt_kernel(
    const float* __restrict__ x, const float* __restrict__ Wq,
    const float* __restrict__ Wk, const float* __restrict__ Wv,
    const float* __restrict__ Wo, const unsigned char* __restrict__ mask,
    u16* __restrict__ xb, u16* __restrict__ Wb, u16* __restrict__ Wob,
    float* __restrict__ cutb) {
  int g = blockIdx.x * 256 + threadIdx.x;
  if (g < 1048576) {
    float4 v = ((const float4*)x)[g];
    ushort4 o;
    o.x = f2bf(v.x); o.y = f2bf(v.y); o.z = f2bf(v.z); o.w = f2bf(v.w);
    ((ushort4*)xb)[g] = o;
  } else if (g < 1310720) {
    int t = g - 1048576;
    int w = t >> 16;
    int off = t & 65535;
    const float* src = (w == 0) ? Wq : (w == 1) ? Wk : (w == 2) ? Wv : Wo;
    u16* dst = (w < 3) ? (Wb + (size_t)w * 262144) : Wob;
    float4 v = ((const float4*)src)[off];
    ushort4 o;
    o.x = f2bf(v.x); o.y = f2bf(v.y); o.z = f2bf(v.z); o.w = f2bf(v.w);
    ((ushort4*)dst)[off] = o;
  } else if (g < 1318912) {
    int t = g - 1310720;              // b*2048 + key
    int key = t & 2047;
    float c = -0.5f * fabsf((float)key - 1024.0f);
    if (mask[t]) c = -1e30f;
    cutb[t] = c;
  }
}

// ---------------------------------------------------------------- QKV GEMM
// Q rows written pre-scaled by 0.125 (exact in bf16).
__global__ __launch_bounds__(256) void gemm_qkv(
    const u16* __restrict__ xb, const u16* __restrict__ Wb,
    const float* __restrict__ bq, const float* __restrict__ bk,
    const float* __restrict__ bv, u16* __restrict__ QK, u16* __restrict__ Vt) {
  __shared__ __align__(16) u16 As[128 * 32];
  __shared__ __align__(16) u16 Bs[128 * 32];
  const int tid = threadIdx.x, lane = tid & 63, wv = tid >> 6;
  const int fr = lane & 15, fg = lane >> 4;
  const int wr = wv >> 1, wc = wv & 1;
  const int m0 = blockIdx.x * 128, n0 = blockIdx.y * 128;
  f32x4 acc[4][4] = {};
  const int c0 = wv * 128;
  for (int kt = 0; kt < 512; kt += 32) {
#pragma unroll
    for (int i = 0; i < 2; ++i) {
      int c = c0 + i * 64 + lane;
      int row = c >> 2, cg = c & 3;
      const u16* ga = xb + (size_t)(m0 + row) * 512 + kt + cg * 8;
      const u16* gb = Wb + (size_t)(n0 + row) * 512 + kt + cg * 8;
      __builtin_amdgcn_global_load_lds(
          (const __attribute__((address_space(1))) void*)ga,
          (__attribute__((address_space(3))) void*)(As + (c0 + i * 64) * 8), 16, 0, 0);
      __builtin_amdgcn_global_load_lds(
          (const __attribute__((address_space(1))) void*)gb,
          (__attribute__((address_space(3))) void*)(Bs + (c0 + i * 64) * 8), 16, 0, 0);
    }
    __syncthreads();
    bf16x8 af[4], bf[4];
#pragma unroll
    for (int mi = 0; mi < 4; ++mi)
      af[mi] = *(const bf16x8*)(As + (wr * 64 + mi * 16 + fr) * 32 + fg * 8);
#pragma unroll
    for (int ni = 0; ni < 4; ++ni)
      bf[ni] = *(const bf16x8*)(Bs + (wc * 64 + ni * 16 + fr) * 32 + fg * 8);
#pragma unroll
    for (int mi = 0; mi < 4; ++mi)
#pragma unroll
      for (int ni = 0; ni < 4; ++ni)
        acc[mi][ni] = __builtin_amdgcn_mfma_f32_16x16x32_bf16(af[mi], bf[ni], acc[mi][ni], 0, 0, 0);
    __syncthreads();
  }
#pragma unroll
  for (int ni = 0; ni < 4; ++ni) {
    int n = n0 + wc * 64 + ni * 16 + fr;
    float bias = (n < 512) ? bq[n] : (n < 1024) ? bk[n - 512] : bv[n - 1024];
#pragma unroll
    for (int mi = 0; mi < 4; ++mi) {
#pragma unroll
      for (int r = 0; r < 4; ++r) {
        int m = m0 + wr * 64 + mi * 16 + fg * 4 + r;
        float o = acc[mi][ni][r] + bias;
        if (n < 512) o *= 0.125f;          // fold 1/sqrt(Dh) into Q
        u16 val = f2bf(o);
        if (n < 1024)
          QK[(size_t)m * 1024 + n] = val;
        else {
          int bb = m >> 11, t = m & 2047;
          Vt[((size_t)bb * 512 + (n - 1024)) * 2048 + t] = val;
        }
      }
    }
  }
}

// ---------------------------------------------------------------- attention
// 512 blocks x 512 threads; 8 waves x 16 q-rows. K/V LDS double-buffered via
// global_load_lds. Raw s_barrier + counted vmcnt: loads issued BEFORE stores
// each iter, so barriers never drain the HBM write queue (16 stores + 2 loads
// in flight -> vmcnt(18)). No other VMEM in the loop (cutb staged in LDS).
__global__ __launch_bounds__(512) void attn_kernel(
    const u16* __restrict__ QK, const u16* __restrict__ Vt,
    const float* __restrict__ cutb, float* __restrict__ attn,
    u16* __restrict__ ctx) {
  __shared__ __align__(16) u16 Kb[2][4096];   // [64 keys][64 dh] swizzled
  __shared__ __align__(16) u16 Vb[2][4096];   // [64 dh][64 keys] swizzled
  __shared__ __align__(16) u16 PL[8][1152];   // per-wave P tile, stride 72
  __shared__ __align__(16) float CB[2048];    // cut+mask bias per key
  const int tid = threadIdx.x, lane = tid & 63, wv = tid >> 6;
  const int fr = lane & 15, fg = lane >> 4;
  const int bid = blockIdx.x;
  const int swz = (bid & 7) * 64 + (bid >> 3);   // XCD-contiguous (b,h)
  const int b = swz >> 7, h = (swz >> 4) & 7, qt = swz & 15;
  const int q0 = qt * 128 + wv * 16;
  const size_t tok0 = (size_t)b * 2048;
  const u16* Qbase = QK + tok0 * 1024 + h * 64;
  const u16* Kbase = QK + tok0 * 1024 + 512 + h * 64;
  const u16* Vbase = Vt + ((size_t)b * 512 + h * 64) * 2048;

  const int srow = tid >> 3, ss = tid & 7, sc = ss ^ (srow & 7);
  const int ldsu = (wv * 64) * 8;

#define STAGE_K(kb0, buf)                                                     \
  __builtin_amdgcn_global_load_lds(                                           \
      (const __attribute__((address_space(1))) void*)(                        \
          Kbase + (size_t)((kb0) + srow) * 1024 + sc * 8),                    \
      (__attribute__((address_space(3))) void*)(Kb[buf] + ldsu), 16, 0, 0)
#define STAGE_V(kb0, buf)                                                     \
  __builtin_amdgcn_global_load_lds(                                           \
      (const __attribute__((address_space(1))) void*)(                        \
          Vbase + (size_t)srow * 2048 + (kb0) + sc * 8),                      \
      (__attribute__((address_space(3))) void*)(Vb[buf] + ldsu), 16, 0, 0)

  bf16x8 aq[2];
#pragma unroll
  for (int c = 0; c < 2; ++c)
    aq[c] = *(const bf16x8*)(Qbase + (size_t)(q0 + fr) * 1024 + c * 32 + fg * 8);
  const float iif = (float)(q0 + fg * 4);

  // stage bias table + first K tile; full drain once
  ((float4*)CB)[tid] = ((const float4*)(cutb + tok0))[tid];
  STAGE_K(0, 0);
  asm volatile("s_waitcnt vmcnt(0) lgkmcnt(0)" ::: "memory");
  __builtin_amdgcn_s_barrier();

  float srw[4] = {0.f, 0.f, 0.f, 0.f};

  // ---- pass A: row exp-sums (no stores in loop; vmcnt(1) only)
  for (int t = 0; t < 32; ++t) {
    const int cur = t & 1;
    if (t < 31) {
      STAGE_K((t + 1) * 64, cur ^ 1);
      asm volatile("s_waitcnt vmcnt(1)" ::: "memory");
    } else {
      asm volatile("s_waitcnt vmcnt(0)" ::: "memory");
    }
    __builtin_amdgcn_s_barrier();
    const int keybase = t * 64;
    const u16* KL = Kb[cur];
#pragma unroll
    for (int kb = 0; kb < 4; ++kb) {
      const int row = kb * 16 + fr;
      const int rx = row & 7;
      bf16x8 k0 = *(const bf16x8*)(KL + row * 64 + ((fg ^ rx) * 8));
      bf16x8 k1 = *(const bf16x8*)(KL + row * 64 + (((4 + fg) ^ rx) * 8));
      f32x4 a = {0.f, 0.f, 0.f, 0.f};
      a = __builtin_amdgcn_mfma_f32_16x16x32_bf16(aq[0], k0, a, 0, 0, 0);
      a = __builtin_amdgcn_mfma_f32_16x16x32_bf16(aq[1], k1, a, 0, 0, 0);
      const int key = keybase + kb * 16 + fr;
      const float cb = CB[key];
      const float dif = iif - (float)key;
#pragma unroll
      for (int r = 0; r < 4; ++r) {
        float S = a[r] + fmaf(-0.02f, fabsf(dif + (float)r), cb);
        srw[r] += __expf(S);
      }
    }
    asm volatile("" ::: "memory");
    __builtin_amdgcn_s_barrier();
  }
#pragma unroll
  for (int d = 1; d < 16; d <<= 1)
#pragma unroll
    for (int i = 0; i < 4; ++i)
      srw[i] += __shfl_xor(srw[i], d, 64);
  float rinv[4];
#pragma unroll
  for (int i = 0; i < 4; ++i) rinv[i] = 1.0f / srw[i];

  // ---- pass B: normalized P writes + PV; stores never drained in-loop
  f32x4 cacc[4] = {};
  float* attn_bh = attn + ((size_t)b * 8 + h) * 2048 * 2048;
  float* arow[4];
#pragma unroll
  for (int r = 0; r < 4; ++r) arow[r] = attn_bh + (size_t)(q0 + fg * 4 + r) * 2048;

  STAGE_K(0, 0);
  STAGE_V(0, 0);
  asm volatile("s_waitcnt vmcnt(0)" ::: "memory");
  __builtin_amdgcn_s_barrier();
  for (int t = 0; t < 32; ++t) {
    const int cur = t & 1;
    if (t < 31) {
      STAGE_K((t + 1) * 64, cur ^ 1);
      STAGE_V((t + 1) * 64, cur ^ 1);
      asm volatile("s_waitcnt vmcnt(18)" ::: "memory");  // 16 stores + 2 new loads
    } else {
      asm volatile("s_waitcnt vmcnt(16)" ::: "memory");  // 16 stores only
    }
    __builtin_amdgcn_s_barrier();
    const int keybase = t * 64;
    const u16* KL = Kb[cur];
    const u16* VL = Vb[cur];
#pragma unroll
    for (int kb = 0; kb < 4; ++kb) {
      const int row = kb * 16 + fr;
      const int rx = row & 7;
      bf16x8 k0 = *(const bf16x8*)(KL + row * 64 + ((fg ^ rx) * 8));
      bf16x8 k1 = *(const bf16x8*)(KL + row * 64 + (((4 + fg) ^ rx) * 8));
      f32x4 a = {0.f, 0.f, 0.f, 0.f};
      a = __builtin_amdgcn_mfma_f32_16x16x32_bf16(aq[0], k0, a, 0, 0, 0);
      a = __builtin_amdgcn_mfma_f32_16x16x32_bf16(aq[1], k1, a, 0, 0, 0);
      const int key = keybase + kb * 16 + fr;
      const float cb = CB[key];
      const float dif = iif - (float)key;
#pragma unroll
      for (int r = 0; r < 4; ++r) {
        float S = a[r] + fmaf(-0.02f, fabsf(dif + (float)r), cb);
        float P = __expf(S) * rinv[r];
        __builtin_nontemporal_store(P, arow[r] + key);
        PL[wv][(fg * 4 + r) * 72 + kb * 16 + fr] = f2bf(P);
      }
    }
#pragma unroll
    for (int kc = 0; kc < 2; ++kc) {
      bf16x8 pa = *(const bf16x8*)(PL[wv] + fr * 72 + kc * 32 + fg * 8);
#pragma unroll
      for (int c4 = 0; c4 < 4; ++c4) {
        const int vrow = c4 * 16 + fr;
        bf16x8 vf = *(const bf16x8*)(VL + vrow * 64 + ((((kc * 4 + fg)) ^ (vrow & 7)) * 8));
        cacc[c4] = __builtin_amdgcn_mfma_f32_16x16x32_bf16(pa, vf, cacc[c4], 0, 0, 0);
      }
    }
    asm volatile("" ::: "memory");
    __builtin_amdgcn_s_barrier();
  }
#pragma unroll
  for (int c4 = 0; c4 < 4; ++c4)
#pragma unroll
    for (int r = 0; r < 4; ++r) {
      int q = q0 + fg * 4 + r;
      ctx[(tok0 + q) * 512 + h * 64 + c4 * 16 + fr] = f2bf(cacc[c4][r]);
    }
#undef STAGE_K
#undef STAGE_V
}

// ---------------------------------------------------------------- out GEMM
__global__ __launch_bounds__(256) void gemm_out(
    const u16* __restrict__ ctx, const u16* __restrict__ Wob,
    const float* __restrict__ bo, float* __restrict__ out) {
  __shared__ __align__(16) u16 As[64 * 32];
  __shared__ __align__(16) u16 Bs[64 * 32];
  const int tid = threadIdx.x, lane = tid & 63, wv = tid >> 6;
  const int fr = lane & 15, fg = lane >> 4;
  const int wr = wv >> 1, wc = wv & 1;
  const int m0 = blockIdx.x * 64, n0 = blockIdx.y * 64;
  f32x4 acc[2][2] = {};
  for (int kt = 0; kt < 512; kt += 32) {
    {
      int row = tid >> 2, cg = tid & 3;
      const u16* ga = ctx + (size_t)(m0 + row) * 512 + kt + cg * 8;
      const u16* gb = Wob + (size_t)(n0 + row) * 512 + kt + cg * 8;
      __builtin_amdgcn_global_load_lds(
          (const __attribute__((address_space(1))) void*)ga,
          (__attribute__((address_space(3))) void*)(As + tid * 8), 16, 0, 0);
      __builtin_amdgcn_global_load_lds(
          (const __attribute__((address_space(1))) void*)gb,
          (__attribute__((address_space(3))) void*)(Bs + tid * 8), 16, 0, 0);
    }
    __syncthreads();
    bf16x8 af[2], bf[2];
#pragma unroll
    for (int mi = 0; mi < 2; ++mi)
      af[mi] = *(const bf16x8*)(As + (wr * 32 + mi * 16 + fr) * 32 + fg * 8);
#pragma unroll
    for (int ni = 0; ni < 2; ++ni)
      bf[ni] = *(const bf16x8*)(Bs + (wc * 32 + ni * 16 + fr) * 32 + fg * 8);
#pragma unroll
    for (int mi = 0; mi < 2; ++mi)
#pragma unroll
      for (int ni = 0; ni < 2; ++ni)
        acc[mi][ni] = __builtin_amdgcn_mfma_f32_16x16x32_bf16(af[mi], bf[ni], acc[mi][ni], 0, 0, 0);
    __syncthreads();
  }
#pragma unroll
  for (int ni = 0; ni < 2; ++ni) {
    int n = n0 + wc * 32 + ni * 16 + fr;
    float bias = bo[n];
#pragma unroll
    for (int mi = 0; mi < 2; ++mi)
#pragma unroll
      for (int r = 0; r < 4; ++r) {
        int m = m0 + wr * 32 + mi * 16 + fg * 4 + r;
        out[(size_t)m * 512 + n] = acc[mi][ni][r] + bias;
      }
  }
}

// ---------------------------------------------------------------- launcher
extern "C" void kernel_launch(void* const* d_in, const int* in_sizes, int n_in,
                              void* d_out, int out_size, void* d_ws, size_t ws_size,
                              hipStream_t stream) {
  const float* x = (const float*)d_in[0];
  const unsigned char* mask = (const unsigned char*)d_in[1];
  const float* Wq = (const float*)d_in[2];
  const float* bq = (const float*)d_in[3];
  const float* Wk = (const float*)d_in[4];
  const float* bk = (const float*)d_in[5];
  const float* Wv = (const float*)d_in[6];
  const float* bv = (const float*)d_in[7];
  const float* Wo = (const float*)d_in[8];
  const float* bo = (const float*)d_in[9];
  float* out = (float*)d_out;
  float* attn = out + (size_t)4 * 2048 * 512;

  char* ws = (char*)d_ws;
  size_t off = 0;
  u16* xb   = (u16*)(ws + off); off += (size_t)8192 * 512 * 2;
  u16* Wb   = (u16*)(ws + off); off += (size_t)1536 * 512 * 2;
  u16* Wob  = (u16*)(ws + off); off += (size_t)512 * 512 * 2;
  u16* QK   = (u16*)(ws + off); off += (size_t)8192 * 1024 * 2;
  u16* Vt   = (u16*)(ws + off); off += (size_t)2048 * 2048 * 2;
  u16* ctx  = (u16*)(ws + off); off += (size_t)8192 * 512 * 2;
  float* cutb = (float*)(ws + off); off += (size_t)8192 * 4;
  if (ws_size < off) return;

  cvt_kernel<<<5152, 256, 0, stream>>>(x, Wq, Wk, Wv, Wo, mask, xb, Wb, Wob, cutb);
  gemm_qkv<<<dim3(64, 12), 256, 0, stream>>>(xb, Wb, bq, bk, bv, QK, Vt);
  attn_kernel<<<512, 512, 0, stream>>>(QK, Vt, cutb, attn, ctx);
  gemm_out<<<dim3(128, 8), 256, 0, stream>>>(ctx, Wob, bo, out);
}